// Round 17
// baseline (73.973 us; speedup 1.0000x reference)
//
#include <hip/hip_runtime.h>
#include <hip/hip_bf16.h>

#define HD   512
#define EPS  1e-5f
#define ASTR 520   // A-tile LDS row stride in shorts

typedef short bf16x8 __attribute__((ext_vector_type(8)));
typedef float f32x4  __attribute__((ext_vector_type(4)));
typedef float f32x4n __attribute__((ext_vector_type(4)));   // native vec for nt builtins

__device__ __forceinline__ float bf2f(unsigned short u) {
    union { unsigned int u32; float f; } c; c.u32 = ((unsigned int)u) << 16; return c.f;
}
__device__ __forceinline__ unsigned short f2bf(float f) {
    __hip_bfloat16 h = __float2bfloat16(f);   // RNE
    return __builtin_bit_cast(unsigned short, h);
}

// ---------------------------------------------------------------------------
// K0: fp = static @ Wf^T + bf        (blocks 0..511, one wave per (b,k) pair)
//     Bt = bf16(Wo) FRAGMENT-MAJOR   (blocks 512..639)   [R13: -6.9 us]
// ---------------------------------------------------------------------------
__global__ void k0_fp_conv(const float* __restrict__ sf, const float* __restrict__ Wf,
                           const float* __restrict__ bfv, const float* __restrict__ Wo,
                           float* __restrict__ fp, unsigned short* __restrict__ Bt) {
    int t = threadIdx.x;
    int blk = blockIdx.x;
    if (blk < 512) {
        int pair = blk * 4 + (t >> 6);          // 0..2047
        int b = pair >> 9;                      // /512
        int k = pair & 511;
        int lane = t & 63;
        const float4* s4 = (const float4*)(sf + b * HD + lane * 8);
        const float4* w4 = (const float4*)(Wf + (size_t)k * HD + lane * 8);
        float4 sa = s4[0], sb = s4[1], wa = w4[0], wb = w4[1];
        float p = sa.x*wa.x + sa.y*wa.y + sa.z*wa.z + sa.w*wa.w
                + sb.x*wb.x + sb.y*wb.y + sb.z*wb.z + sb.w*wb.w;
        #pragma unroll
        for (int off = 32; off; off >>= 1) p += __shfl_xor(p, off);
        if (lane == 0) fp[b * HD + k] = p + bfv[k];
    } else {
        int idx = (blk - 512) * 256 + t;        // 0..32767 = 512 n x 64 kg
        int n  = idx >> 6, kg = idx & 63;
        int g  = n >> 4,  rl = n & 15;
        int s  = kg >> 2, kl = kg & 3;
        const float* src = Wo + (size_t)n * HD + kg * 8;
        float4 a = *(const float4*)src;
        float4 c = *(const float4*)(src + 4);
        union { unsigned short us[8]; uint4 v4; } pk;
        pk.us[0]=f2bf(a.x); pk.us[1]=f2bf(a.y); pk.us[2]=f2bf(a.z); pk.us[3]=f2bf(a.w);
        pk.us[4]=f2bf(c.x); pk.us[5]=f2bf(c.y); pk.us[6]=f2bf(c.z); pk.us[7]=f2bf(c.w);
        *(uint4*)(Bt + (((g * 16 + s) * 64 + kl * 16 + rl) << 3)) = pk.v4;
    }
}

// ---------------------------------------------------------------------------
// DIAGNOSTIC build of the R13 champion (26.57 us): entire body runs TWICE.
// Pass 1 recomputes and rewrites byte-identical results (deterministic,
// harness-safe; same method as R6).  Doubles the dispatch to ~30+ us so the
// fused kernel finally re-enters rocprof's top-5 with post-fragment-major
// counters.  NOT a perf candidate -- a measurement instrument.
// ---------------------------------------------------------------------------
__global__ __launch_bounds__(512) void k_fused(
        const float* __restrict__ temporal,
        const float* __restrict__ fp,
        const float* __restrict__ g1, const float* __restrict__ b1,
        const unsigned short* __restrict__ Bt,  // fragment-major B (bf16)
        const float* __restrict__ bo,
        const float* __restrict__ g2, const float* __restrict__ b2,
        float* __restrict__ out) {
    __shared__ unsigned short As[32 * ASTR];        // 33.3 KB, LN1 result (bf16)
    __shared__ float part_s[8][32], part_q[8][32];  // per-wave LN2 partials
    __shared__ float stat_m[32], stat_r[32];

    int t = threadIdx.x;
    int m0 = blockIdx.x * 32;
    int lane = t & 63, w = t >> 6;
    int rl = lane & 15, kl = lane >> 4;
    int b = m0 >> 11;                                // batch (2048 rows each)
    int c0 = lane * 8;
    const unsigned short* Btw = Bt + ((w * 4) << 13) + lane * 8;   // g-base = w*4

    #pragma unroll 1
    for (int pass = 0; pass < 2; ++pass) {
        __syncthreads();   // pass boundary: prior epilogue's As reads done

        // ---- B prefetch (contiguous 1 KB per frag; fragment-major) ----
        bf16x8 bq[3][4];                             // statically indexed after unroll
        #pragma unroll
        for (int s3 = 0; s3 < 3; ++s3)
            #pragma unroll
            for (int j = 0; j < 4; ++j)
                bq[s3][j] = *(const bf16x8*)(Btw + ((j * 16 + s3) << 9));

        // ---------------- phase 1: LN1 of 32 rows into As ----------------
        float4 f0  = *(const float4*)(fp + b * HD + c0);
        float4 f1  = *(const float4*)(fp + b * HD + c0 + 4);
        float4 g1a = *(const float4*)(g1 + c0), g1b = *(const float4*)(g1 + c0 + 4);
        float4 b1a = *(const float4*)(b1 + c0), b1b = *(const float4*)(b1 + c0 + 4);
        f32x4n xa[4], xb[4];
        #pragma unroll
        for (int r = 0; r < 4; ++r) {                // streaming reads: nt
            const f32x4n* rp = (const f32x4n*)(temporal + (size_t)(m0 + w * 4 + r) * HD + c0);
            xa[r] = __builtin_nontemporal_load(rp);
            xb[r] = __builtin_nontemporal_load(rp + 1);
        }
        #pragma unroll
        for (int r = 0; r < 4; ++r) {
            float v[8];
            v[0]=xa[r][0]+f0.x; v[1]=xa[r][1]+f0.y; v[2]=xa[r][2]+f0.z; v[3]=xa[r][3]+f0.w;
            v[4]=xb[r][0]+f1.x; v[5]=xb[r][1]+f1.y; v[6]=xb[r][2]+f1.z; v[7]=xb[r][3]+f1.w;
            float s = 0.f, q = 0.f;
            #pragma unroll
            for (int j = 0; j < 8; ++j) { s += v[j]; q += v[j] * v[j]; }
            #pragma unroll
            for (int off = 32; off; off >>= 1) { s += __shfl_xor(s, off); q += __shfl_xor(q, off); }
            float mean = s * (1.f / HD);
            float var  = q * (1.f / HD) - mean * mean;
            float rs   = rsqrtf(var + EPS);
            union { unsigned short us[8]; uint4 v4; } pk;
            pk.us[0]=f2bf((v[0]-mean)*rs*g1a.x+b1a.x); pk.us[1]=f2bf((v[1]-mean)*rs*g1a.y+b1a.y);
            pk.us[2]=f2bf((v[2]-mean)*rs*g1a.z+b1a.z); pk.us[3]=f2bf((v[3]-mean)*rs*g1a.w+b1a.w);
            pk.us[4]=f2bf((v[4]-mean)*rs*g1b.x+b1b.x); pk.us[5]=f2bf((v[5]-mean)*rs*g1b.y+b1b.y);
            pk.us[6]=f2bf((v[6]-mean)*rs*g1b.z+b1b.z); pk.us[7]=f2bf((v[7]-mean)*rs*g1b.w+b1b.w);
            *(uint4*)(&As[(w * 4 + r) * ASTR + c0]) = pk.v4;
        }
        __syncthreads();                             // As ready

        // -------- phase 2: GEMM, contiguous B loads, depth-3 prefetch ------
        f32x4 acc[2][4];
        #pragma unroll
        for (int i = 0; i < 2; ++i)
            #pragma unroll
            for (int j = 0; j < 4; ++j) acc[i][j] = (f32x4){0.f, 0.f, 0.f, 0.f};

        #pragma unroll
        for (int step = 0; step < 16; ++step) {
            int kb   = step * 32;
            int slot = step % 3;                     // compile-time after unroll
            bf16x8 a0 = *(const bf16x8*)(&As[rl * ASTR + kb + kl * 8]);
            bf16x8 a1 = *(const bf16x8*)(&As[(rl + 16) * ASTR + kb + kl * 8]);
            #pragma unroll
            for (int j = 0; j < 4; ++j) {
                acc[0][j] = __builtin_amdgcn_mfma_f32_16x16x32_bf16(a0, bq[slot][j], acc[0][j], 0, 0, 0);
                acc[1][j] = __builtin_amdgcn_mfma_f32_16x16x32_bf16(a1, bq[slot][j], acc[1][j], 0, 0, 0);
            }
            if (step + 3 < 16) {                     // refill just-used slot, 3 ahead
                #pragma unroll
                for (int j = 0; j < 4; ++j)
                    bq[slot][j] = *(const bf16x8*)(Btw + ((j * 16 + step + 3) << 9));
            }
        }

        // ---------------- phase 3a: LN2 stats ----------------
        // C/D layout: col = w*64 + j*16 + rl, row = i*16 + kl*4 + reg
        float bov[4], g2v[4], b2v[4];
        #pragma unroll
        for (int j = 0; j < 4; ++j) {
            int col = w * 64 + j * 16 + rl;
            bov[j] = bo[col]; g2v[j] = g2[col]; b2v[j] = b2[col];
        }
        #pragma unroll
        for (int i = 0; i < 2; ++i)
            #pragma unroll
            for (int r2 = 0; r2 < 4; ++r2) {
                int row = i * 16 + kl * 4 + r2;
                float s = 0.f, q = 0.f;
                #pragma unroll
                for (int j = 0; j < 4; ++j) {
                    float o1 = bf2f(As[row * ASTR + w * 64 + j * 16 + rl]);
                    float vv = acc[i][j][r2] + bov[j] + o1;   // out1 + proj
                    acc[i][j][r2] = vv;
                    s += vv; q += vv * vv;
                }
                #pragma unroll
                for (int off = 1; off < 16; off <<= 1) {
                    s += __shfl_xor(s, off); q += __shfl_xor(q, off);
                }
                if (rl == 0) { part_s[w][row] = s; part_q[w][row] = q; }
            }
        __syncthreads();
        if (t < 32) {
            float s = 0.f, q = 0.f;
            #pragma unroll
            for (int ww = 0; ww < 8; ++ww) { s += part_s[ww][t]; q += part_q[ww][t]; }
            float mean = s * (1.f / HD);
            float var  = q * (1.f / HD) - mean * mean;
            stat_m[t] = mean;
            stat_r[t] = rsqrtf(var + EPS);
        }
        __syncthreads();

        // ---------------- phase 3b: apply LN2 + store (direct) ----------
        #pragma unroll
        for (int i = 0; i < 2; ++i)
            #pragma unroll
            for (int r2 = 0; r2 < 4; ++r2) {
                int row  = i * 16 + kl * 4 + r2;
                float mean = stat_m[row], rs = stat_r[row];
                #pragma unroll
                for (int j = 0; j < 4; ++j) {
                    int col = w * 64 + j * 16 + rl;
                    out[(size_t)(m0 + row) * HD + col] = (acc[i][j][r2] - mean) * rs * g2v[j] + b2v[j];
                }
            }
    }
}

// ---------------------------------------------------------------------------
extern "C" void kernel_launch(void* const* d_in, const int* in_sizes, int n_in,
                              void* d_out, int out_size, void* d_ws, size_t ws_size,
                              hipStream_t stream) {
    const float* temporal = (const float*)d_in[0];
    const float* sf  = (const float*)d_in[1];
    // d_in[2] = Wt, d_in[3] = bt : provably unused (softmax over j-constant scores -> uniform)
    const float* Wf  = (const float*)d_in[4];
    const float* bfv = (const float*)d_in[5];
    const float* Wo  = (const float*)d_in[6];
    const float* bo  = (const float*)d_in[7];
    const float* g1  = (const float*)d_in[8];
    const float* b1  = (const float*)d_in[9];
    const float* g2  = (const float*)d_in[10];
    const float* b2  = (const float*)d_in[11];

    char* ws = (char*)d_ws;
    float*          fp = (float*)ws;                      // 8 KB
    unsigned short* Bt = (unsigned short*)(ws + 8192);    // 512 KB, fragment-major B

    k0_fp_conv<<<640, 256, 0, stream>>>(sf, Wf, bfv, Wo, fp, Bt);
    k_fused   <<<256, 512, 0, stream>>>(temporal, fp, g1, b1, Bt, bo, g2, b2, (float*)d_out);
}

// Round 18
// 26.742 us; speedup vs baseline: 2.7661x; 2.7661x over previous
//
#include <hip/hip_runtime.h>
#include <hip/hip_bf16.h>

#define HD   512
#define EPS  1e-5f
#define ASTR 520   // A-tile LDS row stride in shorts
#define DEP  6     // B prefetch depth (R18 lever: 12 -> ~24 outstanding loads/wave)

typedef short bf16x8 __attribute__((ext_vector_type(8)));
typedef float f32x4  __attribute__((ext_vector_type(4)));
typedef float f32x4n __attribute__((ext_vector_type(4)));   // native vec for nt builtins

__device__ __forceinline__ float bf2f(unsigned short u) {
    union { unsigned int u32; float f; } c; c.u32 = ((unsigned int)u) << 16; return c.f;
}
__device__ __forceinline__ unsigned short f2bf(float f) {
    __hip_bfloat16 h = __float2bfloat16(f);   // RNE
    return __builtin_bit_cast(unsigned short, h);
}

// ---------------------------------------------------------------------------
// K0: fp = static @ Wf^T + bf        (blocks 0..511, one wave per (b,k) pair)
//     Bt = bf16(Wo) FRAGMENT-MAJOR   (blocks 512..639)   [R13: -6.9 us]
// Bt layout: [g=n>>4][s=k>>5][kl][rl][8] -> one wave fragment = 1 contiguous KB.
// ---------------------------------------------------------------------------
__global__ void k0_fp_conv(const float* __restrict__ sf, const float* __restrict__ Wf,
                           const float* __restrict__ bfv, const float* __restrict__ Wo,
                           float* __restrict__ fp, unsigned short* __restrict__ Bt) {
    int t = threadIdx.x;
    int blk = blockIdx.x;
    if (blk < 512) {
        int pair = blk * 4 + (t >> 6);          // 0..2047
        int b = pair >> 9;                      // /512
        int k = pair & 511;
        int lane = t & 63;
        const float4* s4 = (const float4*)(sf + b * HD + lane * 8);
        const float4* w4 = (const float4*)(Wf + (size_t)k * HD + lane * 8);
        float4 sa = s4[0], sb = s4[1], wa = w4[0], wb = w4[1];
        float p = sa.x*wa.x + sa.y*wa.y + sa.z*wa.z + sa.w*wa.w
                + sb.x*wb.x + sb.y*wb.y + sb.z*wb.z + sb.w*wb.w;
        #pragma unroll
        for (int off = 32; off; off >>= 1) p += __shfl_xor(p, off);
        if (lane == 0) fp[b * HD + k] = p + bfv[k];
    } else {
        int idx = (blk - 512) * 256 + t;        // 0..32767 = 512 n x 64 kg
        int n  = idx >> 6, kg = idx & 63;
        int g  = n >> 4,  rl = n & 15;
        int s  = kg >> 2, kl = kg & 3;
        const float* src = Wo + (size_t)n * HD + kg * 8;
        float4 a = *(const float4*)src;
        float4 c = *(const float4*)(src + 4);
        union { unsigned short us[8]; uint4 v4; } pk;
        pk.us[0]=f2bf(a.x); pk.us[1]=f2bf(a.y); pk.us[2]=f2bf(a.z); pk.us[3]=f2bf(a.w);
        pk.us[4]=f2bf(c.x); pk.us[5]=f2bf(c.y); pk.us[6]=f2bf(c.z); pk.us[7]=f2bf(c.w);
        *(uint4*)(Bt + (((g * 16 + s) * 64 + kl * 16 + rl) << 3)) = pk.v4;
    }
}

// ---------------------------------------------------------------------------
// Fused: LN1 -> GEMM -> LN2.  R13 body; ONE change: B prefetch depth 3 -> 6
// (bq[6][4], ~+48 VGPR).  R17 diagnostic arithmetic: ~12 outstanding 16-B
// B-loads/wave = 1.5 KB/CU in flight -> ~18 GB/s/CU -> 512 KB of B = ~28 us
// = the observed plateau.  Depth-6 doubles in-flight bytes -> B phase ~halves.
// __launch_bounds__(512,2) caps at 2 waves/SIMD (256-VGPR budget) so the
// allocator doesn't spill chasing occupancy (the R12/R15 pathology).
// ---------------------------------------------------------------------------
__global__ __launch_bounds__(512, 2) void k_fused(
        const float* __restrict__ temporal,
        const float* __restrict__ fp,
        const float* __restrict__ g1, const float* __restrict__ b1,
        const unsigned short* __restrict__ Bt,  // fragment-major B (bf16)
        const float* __restrict__ bo,
        const float* __restrict__ g2, const float* __restrict__ b2,
        float* __restrict__ out) {
    __shared__ unsigned short As[32 * ASTR];        // 33.3 KB, LN1 result (bf16)
    __shared__ float part_s[8][32], part_q[8][32];  // per-wave LN2 partials
    __shared__ float stat_m[32], stat_r[32];

    int t = threadIdx.x;
    int m0 = blockIdx.x * 32;
    int lane = t & 63, w = t >> 6;
    int rl = lane & 15, kl = lane >> 4;
    int b = m0 >> 11;                                // batch (2048 rows each)
    int c0 = lane * 8;

    // ---- B prefetch FIRST: depth-6 rotation, contiguous 1 KB per frag ----
    const unsigned short* Btw = Bt + ((w * 4) << 13) + lane * 8;   // g-base = w*4
    bf16x8 bq[DEP][4];                               // statically indexed after unroll
    #pragma unroll
    for (int s3 = 0; s3 < DEP; ++s3)
        #pragma unroll
        for (int j = 0; j < 4; ++j)
            bq[s3][j] = *(const bf16x8*)(Btw + ((j * 16 + s3) << 9));

    // ---------------- phase 1: LN1 of 32 rows into As ----------------
    float4 f0  = *(const float4*)(fp + b * HD + c0);
    float4 f1  = *(const float4*)(fp + b * HD + c0 + 4);
    float4 g1a = *(const float4*)(g1 + c0), g1b = *(const float4*)(g1 + c0 + 4);
    float4 b1a = *(const float4*)(b1 + c0), b1b = *(const float4*)(b1 + c0 + 4);
    f32x4n xa[4], xb[4];
    #pragma unroll
    for (int r = 0; r < 4; ++r) {                    // streaming reads: nt
        const f32x4n* rp = (const f32x4n*)(temporal + (size_t)(m0 + w * 4 + r) * HD + c0);
        xa[r] = __builtin_nontemporal_load(rp);
        xb[r] = __builtin_nontemporal_load(rp + 1);
    }
    #pragma unroll
    for (int r = 0; r < 4; ++r) {
        float v[8];
        v[0]=xa[r][0]+f0.x; v[1]=xa[r][1]+f0.y; v[2]=xa[r][2]+f0.z; v[3]=xa[r][3]+f0.w;
        v[4]=xb[r][0]+f1.x; v[5]=xb[r][1]+f1.y; v[6]=xb[r][2]+f1.z; v[7]=xb[r][3]+f1.w;
        float s = 0.f, q = 0.f;
        #pragma unroll
        for (int j = 0; j < 8; ++j) { s += v[j]; q += v[j] * v[j]; }
        #pragma unroll
        for (int off = 32; off; off >>= 1) { s += __shfl_xor(s, off); q += __shfl_xor(q, off); }
        float mean = s * (1.f / HD);
        float var  = q * (1.f / HD) - mean * mean;
        float rs   = rsqrtf(var + EPS);
        union { unsigned short us[8]; uint4 v4; } pk;
        pk.us[0]=f2bf((v[0]-mean)*rs*g1a.x+b1a.x); pk.us[1]=f2bf((v[1]-mean)*rs*g1a.y+b1a.y);
        pk.us[2]=f2bf((v[2]-mean)*rs*g1a.z+b1a.z); pk.us[3]=f2bf((v[3]-mean)*rs*g1a.w+b1a.w);
        pk.us[4]=f2bf((v[4]-mean)*rs*g1b.x+b1b.x); pk.us[5]=f2bf((v[5]-mean)*rs*g1b.y+b1b.y);
        pk.us[6]=f2bf((v[6]-mean)*rs*g1b.z+b1b.z); pk.us[7]=f2bf((v[7]-mean)*rs*g1b.w+b1b.w);
        *(uint4*)(&As[(w * 4 + r) * ASTR + c0]) = pk.v4;
    }
    __syncthreads();                                 // As ready

    // -------- phase 2: GEMM, contiguous B loads, depth-6 prefetch --------
    f32x4 acc[2][4];
    #pragma unroll
    for (int i = 0; i < 2; ++i)
        #pragma unroll
        for (int j = 0; j < 4; ++j) acc[i][j] = (f32x4){0.f, 0.f, 0.f, 0.f};

    #pragma unroll
    for (int step = 0; step < 16; ++step) {
        int kb   = step * 32;
        int slot = step % DEP;                       // compile-time after unroll
        bf16x8 a0 = *(const bf16x8*)(&As[rl * ASTR + kb + kl * 8]);
        bf16x8 a1 = *(const bf16x8*)(&As[(rl + 16) * ASTR + kb + kl * 8]);
        #pragma unroll
        for (int j = 0; j < 4; ++j) {
            acc[0][j] = __builtin_amdgcn_mfma_f32_16x16x32_bf16(a0, bq[slot][j], acc[0][j], 0, 0, 0);
            acc[1][j] = __builtin_amdgcn_mfma_f32_16x16x32_bf16(a1, bq[slot][j], acc[1][j], 0, 0, 0);
        }
        if (step + DEP < 16) {                       // refill just-used slot, DEP ahead
            #pragma unroll
            for (int j = 0; j < 4; ++j)
                bq[slot][j] = *(const bf16x8*)(Btw + ((j * 16 + step + DEP) << 9));
        }
    }

    // ---------------- phase 3a: LN2 stats ----------------
    // C/D layout: col = w*64 + j*16 + rl, row = i*16 + kl*4 + reg
    float bov[4], g2v[4], b2v[4];
    #pragma unroll
    for (int j = 0; j < 4; ++j) {
        int col = w * 64 + j * 16 + rl;
        bov[j] = bo[col]; g2v[j] = g2[col]; b2v[j] = b2[col];
    }
    #pragma unroll
    for (int i = 0; i < 2; ++i)
        #pragma unroll
        for (int r2 = 0; r2 < 4; ++r2) {
            int row = i * 16 + kl * 4 + r2;
            float s = 0.f, q = 0.f;
            #pragma unroll
            for (int j = 0; j < 4; ++j) {
                float o1 = bf2f(As[row * ASTR + w * 64 + j * 16 + rl]);
                float vv = acc[i][j][r2] + bov[j] + o1;   // out1 + proj
                acc[i][j][r2] = vv;
                s += vv; q += vv * vv;
            }
            #pragma unroll
            for (int off = 1; off < 16; off <<= 1) {
                s += __shfl_xor(s, off); q += __shfl_xor(q, off);
            }
            if (rl == 0) { part_s[w][row] = s; part_q[w][row] = q; }
        }
    __syncthreads();
    if (t < 32) {
        float s = 0.f, q = 0.f;
        #pragma unroll
        for (int ww = 0; ww < 8; ++ww) { s += part_s[ww][t]; q += part_q[ww][t]; }
        float mean = s * (1.f / HD);
        float var  = q * (1.f / HD) - mean * mean;
        stat_m[t] = mean;
        stat_r[t] = rsqrtf(var + EPS);
    }
    __syncthreads();

    // ---------------- phase 3b: apply LN2 + store (direct, R13) ----------
    #pragma unroll
    for (int i = 0; i < 2; ++i)
        #pragma unroll
        for (int r2 = 0; r2 < 4; ++r2) {
            int row  = i * 16 + kl * 4 + r2;
            float mean = stat_m[row], rs = stat_r[row];
            #pragma unroll
            for (int j = 0; j < 4; ++j) {
                int col = w * 64 + j * 16 + rl;
                out[(size_t)(m0 + row) * HD + col] = (acc[i][j][r2] - mean) * rs * g2v[j] + b2v[j];
            }
        }
}

// ---------------------------------------------------------------------------
extern "C" void kernel_launch(void* const* d_in, const int* in_sizes, int n_in,
                              void* d_out, int out_size, void* d_ws, size_t ws_size,
                              hipStream_t stream) {
    const float* temporal = (const float*)d_in[0];
    const float* sf  = (const float*)d_in[1];
    // d_in[2] = Wt, d_in[3] = bt : provably unused (softmax over j-constant scores -> uniform)
    const float* Wf  = (const float*)d_in[4];
    const float* bfv = (const float*)d_in[5];
    const float* Wo  = (const float*)d_in[6];
    const float* bo  = (const float*)d_in[7];
    const float* g1  = (const float*)d_in[8];
    const float* b1  = (const float*)d_in[9];
    const float* g2  = (const float*)d_in[10];
    const float* b2  = (const float*)d_in[11];

    char* ws = (char*)d_ws;
    float*          fp = (float*)ws;                      // 8 KB
    unsigned short* Bt = (unsigned short*)(ws + 8192);    // 512 KB, fragment-major B

    k0_fp_conv<<<640, 256, 0, stream>>>(sf, Wf, bfv, Wo, fp, Bt);
    k_fused   <<<256, 512, 0, stream>>>(temporal, fp, g1, b1, Bt, bo, g2, b2, (float*)d_out);
}

// Round 19
// 25.969 us; speedup vs baseline: 2.8485x; 1.0298x over previous
//
#include <hip/hip_runtime.h>
#include <hip/hip_bf16.h>

#define HD   512
#define EPS  1e-5f
#define ASTR 520   // A-tile LDS row stride in shorts

typedef short bf16x8 __attribute__((ext_vector_type(8)));
typedef float f32x4  __attribute__((ext_vector_type(4)));

__device__ __forceinline__ float bf2f(unsigned short u) {
    union { unsigned int u32; float f; } c; c.u32 = ((unsigned int)u) << 16; return c.f;
}
__device__ __forceinline__ unsigned short f2bf(float f) {
    __hip_bfloat16 h = __float2bfloat16(f);   // RNE
    return __builtin_bit_cast(unsigned short, h);
}

// ---------------------------------------------------------------------------
// K0: fp = static @ Wf^T + bf        (blocks 0..511, one wave per (b,k) pair)
//     Bt = bf16(Wo) FRAGMENT-MAJOR   (blocks 512..639)   [R13: -6.9 us]
// Bt layout: [g=n>>4][s=k>>5][kl][rl][8] -> one wave fragment = 1 contiguous KB.
// ---------------------------------------------------------------------------
__global__ void k0_fp_conv(const float* __restrict__ sf, const float* __restrict__ Wf,
                           const float* __restrict__ bfv, const float* __restrict__ Wo,
                           float* __restrict__ fp, unsigned short* __restrict__ Bt) {
    int t = threadIdx.x;
    int blk = blockIdx.x;
    if (blk < 512) {
        int pair = blk * 4 + (t >> 6);          // 0..2047
        int b = pair >> 9;                      // /512
        int k = pair & 511;
        int lane = t & 63;
        const float4* s4 = (const float4*)(sf + b * HD + lane * 8);
        const float4* w4 = (const float4*)(Wf + (size_t)k * HD + lane * 8);
        float4 sa = s4[0], sb = s4[1], wa = w4[0], wb = w4[1];
        float p = sa.x*wa.x + sa.y*wa.y + sa.z*wa.z + sa.w*wa.w
                + sb.x*wb.x + sb.y*wb.y + sb.z*wb.z + sb.w*wb.w;
        #pragma unroll
        for (int off = 32; off; off >>= 1) p += __shfl_xor(p, off);
        if (lane == 0) fp[b * HD + k] = p + bfv[k];
    } else {
        int idx = (blk - 512) * 256 + t;        // 0..32767 = 512 n x 64 kg
        int n  = idx >> 6, kg = idx & 63;
        int g  = n >> 4,  rl = n & 15;
        int s  = kg >> 2, kl = kg & 3;
        const float* src = Wo + (size_t)n * HD + kg * 8;
        float4 a = *(const float4*)src;
        float4 c = *(const float4*)(src + 4);
        union { unsigned short us[8]; uint4 v4; } pk;
        pk.us[0]=f2bf(a.x); pk.us[1]=f2bf(a.y); pk.us[2]=f2bf(a.z); pk.us[3]=f2bf(a.w);
        pk.us[4]=f2bf(c.x); pk.us[5]=f2bf(c.y); pk.us[6]=f2bf(c.z); pk.us[7]=f2bf(c.w);
        *(uint4*)(Bt + (((g * 16 + s) * 64 + kl * 16 + rl) << 3)) = pk.v4;
    }
}

// ---------------------------------------------------------------------------
// Fused: LN1 -> GEMM -> LN2.  R13 body; ONE mechanism changed: LN1's
// temporal loads are now CACHED (nt dropped) and each load instruction
// covers a contiguous 1 KB (lane*16B, two half-rows) instead of 2x16B at
// 32-B lane stride.  The old nt+strided pattern touched every 128-B line
// twice with L2 bypassed -> ~2x HBM fetch of temporal (the ~15 MB/pass
// FETCH excess in R17's diagnostic).  As content/layout unchanged.
// ---------------------------------------------------------------------------
__global__ __launch_bounds__(512) void k_fused(
        const float* __restrict__ temporal,
        const float* __restrict__ fp,
        const float* __restrict__ g1, const float* __restrict__ b1,
        const unsigned short* __restrict__ Bt,  // fragment-major B (bf16)
        const float* __restrict__ bo,
        const float* __restrict__ g2, const float* __restrict__ b2,
        float* __restrict__ out) {
    __shared__ unsigned short As[32 * ASTR];        // 33.3 KB, LN1 result (bf16)
    __shared__ float part_s[8][32], part_q[8][32];  // per-wave LN2 partials
    __shared__ float stat_m[32], stat_r[32];

    int t = threadIdx.x;
    int m0 = blockIdx.x * 32;
    int lane = t & 63, w = t >> 6;
    int rl = lane & 15, kl = lane >> 4;
    int b = m0 >> 11;                                // batch (2048 rows each)
    int c4 = lane * 4;                               // first-half col (floats)

    // ---- B prefetch FIRST: depth-3 rotation, contiguous 1 KB per frag ----
    const unsigned short* Btw = Bt + ((w * 4) << 13) + lane * 8;   // g-base = w*4
    bf16x8 bq[3][4];                                 // statically indexed after unroll
    #pragma unroll
    for (int s3 = 0; s3 < 3; ++s3)
        #pragma unroll
        for (int j = 0; j < 4; ++j)
            bq[s3][j] = *(const bf16x8*)(Btw + ((j * 16 + s3) << 9));

    // ---------------- phase 1: LN1 of 32 rows into As ----------------
    // lane covers cols [c4, c4+4) and [256+c4, 256+c4+4): each wave load
    // instruction = one contiguous 1 KB block (full 128-B lines, used once).
    float4 f0  = *(const float4*)(fp + b * HD + c4);
    float4 f1  = *(const float4*)(fp + b * HD + 256 + c4);
    float4 g1a = *(const float4*)(g1 + c4), g1b = *(const float4*)(g1 + 256 + c4);
    float4 b1a = *(const float4*)(b1 + c4), b1b = *(const float4*)(b1 + 256 + c4);
    float4 xa[4], xb[4];
    #pragma unroll
    for (int r = 0; r < 4; ++r) {                    // cached reads (L2 merges)
        const float* rp = temporal + (size_t)(m0 + w * 4 + r) * HD;
        xa[r] = *(const float4*)(rp + c4);
        xb[r] = *(const float4*)(rp + 256 + c4);
    }
    #pragma unroll
    for (int r = 0; r < 4; ++r) {
        float v[8];
        v[0]=xa[r].x+f0.x; v[1]=xa[r].y+f0.y; v[2]=xa[r].z+f0.z; v[3]=xa[r].w+f0.w;
        v[4]=xb[r].x+f1.x; v[5]=xb[r].y+f1.y; v[6]=xb[r].z+f1.z; v[7]=xb[r].w+f1.w;
        float s = 0.f, q = 0.f;
        #pragma unroll
        for (int j = 0; j < 8; ++j) { s += v[j]; q += v[j] * v[j]; }
        #pragma unroll
        for (int off = 32; off; off >>= 1) { s += __shfl_xor(s, off); q += __shfl_xor(q, off); }
        float mean = s * (1.f / HD);
        float var  = q * (1.f / HD) - mean * mean;
        float rs   = rsqrtf(var + EPS);
        int row = w * 4 + r;
        union { unsigned short us[4]; uint2 v2; } pa, pb;
        pa.us[0]=f2bf((v[0]-mean)*rs*g1a.x+b1a.x); pa.us[1]=f2bf((v[1]-mean)*rs*g1a.y+b1a.y);
        pa.us[2]=f2bf((v[2]-mean)*rs*g1a.z+b1a.z); pa.us[3]=f2bf((v[3]-mean)*rs*g1a.w+b1a.w);
        pb.us[0]=f2bf((v[4]-mean)*rs*g1b.x+b1b.x); pb.us[1]=f2bf((v[5]-mean)*rs*g1b.y+b1b.y);
        pb.us[2]=f2bf((v[6]-mean)*rs*g1b.z+b1b.z); pb.us[3]=f2bf((v[7]-mean)*rs*g1b.w+b1b.w);
        *(uint2*)(&As[row * ASTR + c4])       = pa.v2;
        *(uint2*)(&As[row * ASTR + 256 + c4]) = pb.v2;
    }
    __syncthreads();                                 // As ready

    // -------- phase 2: GEMM, contiguous B loads, depth-3 prefetch --------
    f32x4 acc[2][4];
    #pragma unroll
    for (int i = 0; i < 2; ++i)
        #pragma unroll
        for (int j = 0; j < 4; ++j) acc[i][j] = (f32x4){0.f, 0.f, 0.f, 0.f};

    #pragma unroll
    for (int step = 0; step < 16; ++step) {
        int kb   = step * 32;
        int slot = step % 3;                         // compile-time after unroll
        bf16x8 a0 = *(const bf16x8*)(&As[rl * ASTR + kb + kl * 8]);
        bf16x8 a1 = *(const bf16x8*)(&As[(rl + 16) * ASTR + kb + kl * 8]);
        #pragma unroll
        for (int j = 0; j < 4; ++j) {
            acc[0][j] = __builtin_amdgcn_mfma_f32_16x16x32_bf16(a0, bq[slot][j], acc[0][j], 0, 0, 0);
            acc[1][j] = __builtin_amdgcn_mfma_f32_16x16x32_bf16(a1, bq[slot][j], acc[1][j], 0, 0, 0);
        }
        if (step + 3 < 16) {                         // refill just-used slot, 3 ahead
            #pragma unroll
            for (int j = 0; j < 4; ++j)
                bq[slot][j] = *(const bf16x8*)(Btw + ((j * 16 + step + 3) << 9));
        }
    }

    // ---------------- phase 3a: LN2 stats ----------------
    // C/D layout: col = w*64 + j*16 + rl, row = i*16 + kl*4 + reg
    float bov[4], g2v[4], b2v[4];
    #pragma unroll
    for (int j = 0; j < 4; ++j) {
        int col = w * 64 + j * 16 + rl;
        bov[j] = bo[col]; g2v[j] = g2[col]; b2v[j] = b2[col];
    }
    #pragma unroll
    for (int i = 0; i < 2; ++i)
        #pragma unroll
        for (int r2 = 0; r2 < 4; ++r2) {
            int row = i * 16 + kl * 4 + r2;
            float s = 0.f, q = 0.f;
            #pragma unroll
            for (int j = 0; j < 4; ++j) {
                float o1 = bf2f(As[row * ASTR + w * 64 + j * 16 + rl]);
                float vv = acc[i][j][r2] + bov[j] + o1;   // out1 + proj
                acc[i][j][r2] = vv;
                s += vv; q += vv * vv;
            }
            #pragma unroll
            for (int off = 1; off < 16; off <<= 1) {
                s += __shfl_xor(s, off); q += __shfl_xor(q, off);
            }
            if (rl == 0) { part_s[w][row] = s; part_q[w][row] = q; }
        }
    __syncthreads();
    if (t < 32) {
        float s = 0.f, q = 0.f;
        #pragma unroll
        for (int ww = 0; ww < 8; ++ww) { s += part_s[ww][t]; q += part_q[ww][t]; }
        float mean = s * (1.f / HD);
        float var  = q * (1.f / HD) - mean * mean;
        stat_m[t] = mean;
        stat_r[t] = rsqrtf(var + EPS);
    }
    __syncthreads();

    // ---------------- phase 3b: apply LN2 + store (direct, R13) ----------
    #pragma unroll
    for (int i = 0; i < 2; ++i)
        #pragma unroll
        for (int r2 = 0; r2 < 4; ++r2) {
            int row  = i * 16 + kl * 4 + r2;
            float mean = stat_m[row], rs = stat_r[row];
            #pragma unroll
            for (int j = 0; j < 4; ++j) {
                int col = w * 64 + j * 16 + rl;
                out[(size_t)(m0 + row) * HD + col] = (acc[i][j][r2] - mean) * rs * g2v[j] + b2v[j];
            }
        }
}

// ---------------------------------------------------------------------------
extern "C" void kernel_launch(void* const* d_in, const int* in_sizes, int n_in,
                              void* d_out, int out_size, void* d_ws, size_t ws_size,
                              hipStream_t stream) {
    const float* temporal = (const float*)d_in[0];
    const float* sf  = (const float*)d_in[1];
    // d_in[2] = Wt, d_in[3] = bt : provably unused (softmax over j-constant scores -> uniform)
    const float* Wf  = (const float*)d_in[4];
    const float* bfv = (const float*)d_in[5];
    const float* Wo  = (const float*)d_in[6];
    const float* bo  = (const float*)d_in[7];
    const float* g1  = (const float*)d_in[8];
    const float* b1  = (const float*)d_in[9];
    const float* g2  = (const float*)d_in[10];
    const float* b2  = (const float*)d_in[11];

    char* ws = (char*)d_ws;
    float*          fp = (float*)ws;                      // 8 KB
    unsigned short* Bt = (unsigned short*)(ws + 8192);    // 512 KB, fragment-major B

    k0_fp_conv<<<640, 256, 0, stream>>>(sf, Wf, bfv, Wo, fp, Bt);
    k_fused   <<<256, 512, 0, stream>>>(temporal, fp, g1, b1, Bt, bo, g2, b2, (float*)d_out);
}